// Round 13
// baseline (443.197 us; speedup 1.0000x reference)
//
#include <hip/hip_runtime.h>

#define CH 128
#define NHEAD 4
#define CAP 16

typedef float f32x4 __attribute__((ext_vector_type(4)));
typedef short bf16x8 __attribute__((ext_vector_type(8)));

static __device__ __forceinline__ float b2f(unsigned short u){
  union { unsigned int u; float f; } x; x.u = ((unsigned int)u) << 16; return x.f;
}
static __device__ __forceinline__ unsigned short f2b(float f){
  union { float f; unsigned int u; } x; x.f = f;
  unsigned int r = x.u + 0x7FFFu + ((x.u >> 16) & 1u);
  return (unsigned short)(r >> 16);
}

static __host__ __device__ inline int cdiv_i(int a, int b){ return (a + b - 1) / b; }

// ---------------- bucket scatter: one atomic pass builds per-node edge lists ----------------
__global__ __launch_bounds__(256) void hg_bscat(
    const int* __restrict__ dstU, const int* __restrict__ srcU,
    int* __restrict__ cntU, int* __restrict__ slotsU,
    int* __restrict__ spNU, int* __restrict__ spDU, int* __restrict__ spSU,
    const int* __restrict__ dstI, const int* __restrict__ srcI,
    int* __restrict__ cntI, int* __restrict__ slotsI,
    int* __restrict__ spNI, int* __restrict__ spDI, int* __restrict__ spSI,
    int E, int half){
  int b = blockIdx.x;
  const int *dst, *src; int *cnt, *slots, *spN, *spD, *spS; int lb;
  if (b < half){ dst=dstU; src=srcU; cnt=cntU; slots=slotsU; spN=spNU; spD=spDU; spS=spSU; lb=b; }
  else { dst=dstI; src=srcI; cnt=cntI; slots=slotsI; spN=spNI; spD=spDI; spS=spSI; lb=b-half; }
  int t = lb*256 + threadIdx.x;
  if (t >= E) return;
  int d = dst[t], s = src[t];
  int pos = atomicAdd(&cnt[d], 1);
  if (pos < CAP){
    slots[(size_t)d*CAP + pos] = s;
  } else {
    int sp = atomicAdd(spN, 1);
    spD[sp] = d; spS[sp] = s;
  }
}

// ---------------- prep1: cvt (both tensors) || wprep ----------------
__global__ __launch_bounds__(256) void hg_prep1(
    const float* __restrict__ xu, unsigned short* __restrict__ yu, long nuv, long nut, int bu,
    const float* __restrict__ xi, unsigned short* __restrict__ yi, long niv, long nit, int bi,
    const float* __restrict__ Wsrc_iu, const float* __restrict__ Wsrc_ui,
    const float* __restrict__ Wdst_iu, const float* __restrict__ Wdst_ui,
    const float* __restrict__ asrc_iu, const float* __restrict__ asrc_ui,
    const float* __restrict__ adst_iu, const float* __restrict__ adst_ui,
    unsigned short* __restrict__ wtAll, float* __restrict__ wdAll, float* __restrict__ wsAll){
  int b = blockIdx.x, tid = threadIdx.x;
  if (b < bu + bi){
    const float* x; unsigned short* y; long nv, nt; int lb;
    if (b < bu){ x = xu; y = yu; nv = nuv; nt = nut; lb = b; }
    else { x = xi; y = yi; nv = niv; nt = nit; lb = b - bu; }
    long t = ((long)lb * 256 + tid) * 4;
    if (t >= nt) return;
    ushort4 o;
    if (t + 3 < nv){
      float4 v = *(const float4*)(x + t);
      o.x = f2b(v.x); o.y = f2b(v.y); o.z = f2b(v.z); o.w = f2b(v.w);
    } else {
      o.x = o.y = o.z = o.w = 0;
    }
    *(ushort4*)(y + t) = o;
  } else {
    int wb = b - bu - bi;
    int ld = wb / 68, r = wb % 68;
    int l = ld >> 1, d = ld & 1;
    const float* Ws = (d ? Wsrc_ui : Wsrc_iu) + (size_t)l*CH*CH;
    const float* Wd = (d ? Wdst_ui : Wdst_iu) + (size_t)l*CH*CH;
    const float* as_ = (d ? asrc_ui : asrc_iu) + (size_t)l*CH;
    const float* ad  = (d ? adst_ui : adst_iu) + (size_t)l*CH;
    unsigned short* wt = wtAll + (size_t)ld*CH*CH;
    float* wd_o = wdAll + (size_t)ld*CH*4;
    float* ws_o = wsAll + (size_t)ld*CH*4;
    if (r < 64){
      int t = r*256 + tid;
      int k = t >> 7, n = t & 127;
      wt[n*CH + k] = f2b(Ws[t]);
    } else if (r < 66){
      int t = (r - 64)*256 + tid;
      int k = t >> 2, h = t & 3;
      float acc = 0.f;
      #pragma unroll 8
      for (int c = 0; c < 32; ++c) acc += Wd[k*CH + h*32 + c] * ad[h*32 + c];
      wd_o[k*4 + h] = acc;
    } else {
      int t = (r - 66)*256 + tid;
      int k = t >> 2, h = t & 3;
      float acc = 0.f;
      #pragma unroll 8
      for (int c = 0; c < 32; ++c) acc += Ws[k*CH + h*32 + c] * as_[h*32 + c];
      ws_o[k*4 + h] = acc;
    }
  }
}

// ---------------- GEMM both directions + (optional) esed blocks appended ----------------
__global__ __launch_bounds__(256) void hg_gemm2(const unsigned short* __restrict__ X0,
                                                const unsigned short* __restrict__ W0,
                                                unsigned short* __restrict__ Y0, int n0,
                                                const unsigned short* __restrict__ X1,
                                                const unsigned short* __restrict__ W1,
                                                unsigned short* __restrict__ Y1, int n01,
                                                const float* __restrict__ wsU, const float* __restrict__ wdU,
                                                float* __restrict__ esU, float* __restrict__ edU, int NU, int bU,
                                                const float* __restrict__ wsI, const float* __restrict__ wdI,
                                                float* __restrict__ esI, float* __restrict__ edI, int NI){
  __shared__ unsigned short Abuf[CH*CH];
  __shared__ unsigned short Bbuf[CH*CH];
  int tid = threadIdx.x;
  int b = blockIdx.x;

  if (b >= n01){
    // ---- esed path (layer-0 only) ----
    int eb = b - n01;
    const unsigned short* x; const float *wsf, *wdf; float *es, *ed; int N, lb;
    if (eb < bU){ x = X1; wsf = wsU; wdf = wdU; es = esU; ed = edU; N = NU; lb = eb; }
    else { x = X0; wsf = wsI; wdf = wdI; es = esI; ed = edI; N = NI; lb = eb - bU; }
    int n = lb * 256 + tid;
    if (n >= N) return;
    const uint4* row = (const uint4*)(x + (size_t)n * CH);
    float s0=0.f,s1=0.f,s2=0.f,s3=0.f,d0=0.f,d1=0.f,d2=0.f,d3=0.f;
    #pragma unroll
    for (int b8 = 0; b8 < 16; ++b8){
      uint4 v = row[b8];
      unsigned int u[4] = {v.x, v.y, v.z, v.w};
      #pragma unroll
      for (int q = 0; q < 4; ++q){
        int k = b8*8 + 2*q;
        float x0 = b2f((unsigned short)(u[q] & 0xffffu));
        float x1 = b2f((unsigned short)(u[q] >> 16));
        float4 a0 = *(const float4*)(wsf + (size_t)k*4);
        float4 a1 = *(const float4*)(wsf + (size_t)(k+1)*4);
        float4 c0 = *(const float4*)(wdf + (size_t)k*4);
        float4 c1 = *(const float4*)(wdf + (size_t)(k+1)*4);
        s0 += x0*a0.x + x1*a1.x;  s1 += x0*a0.y + x1*a1.y;
        s2 += x0*a0.z + x1*a1.z;  s3 += x0*a0.w + x1*a1.w;
        d0 += x0*c0.x + x1*c1.x;  d1 += x0*c0.y + x1*c1.y;
        d2 += x0*c0.z + x1*c1.z;  d3 += x0*c0.w + x1*c1.w;
      }
    }
    float* eo = es + (size_t)n*4;
    eo[0]=s0; eo[1]=s1; eo[2]=s2; eo[3]=s3;
    float* do_ = ed + (size_t)n*4;
    do_[0]=d0; do_[1]=d1; do_[2]=d2; do_[3]=d3;
    return;
  }

  // ---- GEMM path ----
  size_t bm = b;
  const unsigned short* X; const unsigned short* W; unsigned short* Y;
  if ((int)bm < n0){ X = X0; W = W0; Y = Y0; }
  else { X = X1; W = W1; Y = Y1; bm -= n0; }
  const unsigned short* xsrc = X + bm * (size_t)(CH*CH);
  #pragma unroll
  for (int it = 0; it < 8; ++it){
    int G = it*256 + tid;
    int m = G >> 4, kg = G & 15;
    int sw = kg ^ (m & 7);
    uint4 va = ((const uint4*)xsrc)[G];
    ((uint4*)Abuf)[m*16 + sw] = va;
    uint4 vb = ((const uint4*)W)[G];
    ((uint4*)Bbuf)[m*16 + sw] = vb;
  }
  __syncthreads();

  int lane = tid & 63, wid = tid >> 6;
  int wr = wid >> 1, wc = wid & 1;
  int l15 = lane & 15, l4 = lane >> 4;
  f32x4 acc[4][4] = {};

  #pragma unroll
  for (int kk = 0; kk < 4; ++kk){
    int kgq = kk*4 + l4;
    bf16x8 af[4], bfr[4];
    #pragma unroll
    for (int i = 0; i < 4; ++i){
      int r = wr*64 + i*16 + l15;
      af[i] = *(const bf16x8*)&Abuf[(r*16 + (kgq ^ (r & 7))) * 8];
      int c = wc*64 + i*16 + l15;
      bfr[i] = *(const bf16x8*)&Bbuf[(c*16 + (kgq ^ (c & 7))) * 8];
    }
    #pragma unroll
    for (int i = 0; i < 4; ++i)
      #pragma unroll
      for (int j = 0; j < 4; ++j)
        acc[i][j] = __builtin_amdgcn_mfma_f32_16x16x32_bf16(af[i], bfr[j], acc[i][j], 0, 0, 0);
  }

  #pragma unroll
  for (int i = 0; i < 4; ++i){
    #pragma unroll
    for (int j = 0; j < 4; ++j){
      int r0 = wr*64 + i*16 + l4*4;
      int c  = wc*64 + j*16 + l15;
      size_t base = (bm*CH + r0) * (size_t)CH + c;
      #pragma unroll
      for (int v = 0; v < 4; ++v)
        Y[base + (size_t)v*CH] = f2b(acc[i][j][v]);
    }
  }
}

// ---------------- fused agg: bucket lists, clamped gathers, optional next-layer es/ed fusion ----------------
#define AGG_ROUND(DEPTH)                                                          \
  for (int j0 = 0; j0 < nb16; j0 += DEPTH){                                       \
    uint4 hv[DEPTH]; float lg[DEPTH];                                             \
    _Pragma("unroll")                                                             \
    for (int k = 0; k < DEPTH; ++k){                                              \
      int jk = j0 + k; jk = (jk < nb16) ? jk : (nb16 - 1);                        \
      int s = __shfl(sj, g*16 + jk);                                              \
      hv[k] = *(const uint4*)(hs + (size_t)s*CH + c16*8);                         \
      lg[k] = eslog[(size_t)s*4 + h];                                             \
    }                                                                             \
    _Pragma("unroll")                                                             \
    for (int k = 0; k < DEPTH; ++k){                                              \
      float ev = lg[k] + edv;                                                     \
      ev = (ev > 0.f) ? ev : 0.2f * ev;                                           \
      float w = ((j0 + k) < nb16) ? __expf(ev) : 0.f;                             \
      zp += w;                                                                    \
      unsigned int u0 = hv[k].x, u1 = hv[k].y, u2 = hv[k].z, u3 = hv[k].w;        \
      pacc[0] += w * b2f((unsigned short)(u0 & 0xffffu));                         \
      pacc[1] += w * b2f((unsigned short)(u0 >> 16));                             \
      pacc[2] += w * b2f((unsigned short)(u1 & 0xffffu));                         \
      pacc[3] += w * b2f((unsigned short)(u1 >> 16));                             \
      pacc[4] += w * b2f((unsigned short)(u2 & 0xffffu));                         \
      pacc[5] += w * b2f((unsigned short)(u2 >> 16));                             \
      pacc[6] += w * b2f((unsigned short)(u3 & 0xffffu));                         \
      pacc[7] += w * b2f((unsigned short)(u3 >> 16));                             \
    }                                                                             \
  }

__global__ __launch_bounds__(256) void hg_agg2(
    const int* __restrict__ cntU, const int* __restrict__ slotsU,
    const int* __restrict__ spNU, const int* __restrict__ spDU, const int* __restrict__ spSU,
    const float* __restrict__ eslogU, const float* __restrict__ edU,
    const unsigned short* __restrict__ hsI,
    const float* __restrict__ biasU, const float* __restrict__ lnwU, const float* __restrict__ lnbU,
    unsigned short* __restrict__ xoutU, int NU, int nbU,
    const float* __restrict__ wsNU, const float* __restrict__ wdNU,
    float* __restrict__ esNU, float* __restrict__ edNU,
    const int* __restrict__ cntI, const int* __restrict__ slotsI,
    const int* __restrict__ spNI, const int* __restrict__ spDI, const int* __restrict__ spSI,
    const float* __restrict__ eslogI, const float* __restrict__ edI,
    const unsigned short* __restrict__ hsU,
    const float* __restrict__ biasI, const float* __restrict__ lnwI, const float* __restrict__ lnbI,
    unsigned short* __restrict__ xoutI, int NI,
    const float* __restrict__ wsNI, const float* __restrict__ wdNI,
    float* __restrict__ esNI, float* __restrict__ edNI,
    int fuse){
  int b = blockIdx.x;
  bool isU = (b < nbU);
  const int *cnt, *slots, *spN, *spD, *spS; const float *eslog, *ed;
  const unsigned short* hs; const float *bias, *lnw, *lnb;
  const float *wsN, *wdN; float *esN, *edN;
  unsigned short* xout; int Ndst, lb;
  if (isU){
    cnt = cntU; slots = slotsU; spN = spNU; spD = spDU; spS = spSU;
    eslog = eslogU; ed = edU; hs = hsI;
    bias = biasU; lnw = lnwU; lnb = lnbU; xout = xoutU; Ndst = NU; lb = b;
    wsN = wsNU; wdN = wdNU; esN = esNU; edN = edNU;
  } else {
    cnt = cntI; slots = slotsI; spN = spNI; spD = spDI; spS = spSI;
    eslog = eslogI; ed = edI; hs = hsU;
    bias = biasI; lnw = lnwI; lnb = lnbI; xout = xoutI; Ndst = NI; lb = b - nbU;
    wsN = wsNI; wdN = wdNI; esN = esNI; edN = edNI;
  }
  int tid = threadIdx.x;
  int lane = tid & 63, wid = tid >> 6;
  int g = lane >> 4, c16 = lane & 15, h = c16 >> 2;
  int node = lb * 16 + wid * 4 + g;
  uint4* orow = (uint4*)(xout + (size_t)node * CH);
  if (node >= Ndst){
    uint4 z4 = {0,0,0,0};
    orow[c16] = z4;
    return;
  }

  int deg = cnt[node];
  float edv = ed[(size_t)node*4 + h];
  float pacc[8] = {0.f,0.f,0.f,0.f,0.f,0.f,0.f,0.f};
  float zp = 0.f;

  int nb16 = deg < CAP ? deg : CAP;
  const int* sl = slots + (size_t)node * CAP;
  int jj = (c16 < nb16) ? c16 : (nb16 > 0 ? nb16 - 1 : 0);
  int sj = sl[jj];

  if (isU){
    AGG_ROUND(8)
  } else {
    AGG_ROUND(4)
  }
  // rare spill tail (deg > CAP)
  if (deg > CAP){
    int sn = *spN;
    for (int j = 0; j < sn; ++j){
      if (spD[j] == node){
        int s = spS[j];
        float ev = eslog[(size_t)s*4 + h] + edv;
        ev = (ev > 0.f) ? ev : 0.2f * ev;
        float w = __expf(ev);
        zp += w;
        uint4 hv1 = *(const uint4*)(hs + (size_t)s*CH + c16*8);
        unsigned int u[4] = {hv1.x, hv1.y, hv1.z, hv1.w};
        #pragma unroll
        for (int q = 0; q < 4; ++q){
          pacc[2*q]   += w * b2f((unsigned short)(u[q] & 0xffffu));
          pacc[2*q+1] += w * b2f((unsigned short)(u[q] >> 16));
        }
      }
    }
  }

  float rz = (zp > 0.f) ? (1.f / zp) : 0.f;
  float4 b0 = *(const float4*)(bias + c16*8);
  float4 b1 = *(const float4*)(bias + c16*8 + 4);
  float r[8];
  r[0] = pacc[0]*rz + b0.x; r[1] = pacc[1]*rz + b0.y;
  r[2] = pacc[2]*rz + b0.z; r[3] = pacc[3]*rz + b0.w;
  r[4] = pacc[4]*rz + b1.x; r[5] = pacc[5]*rz + b1.y;
  r[6] = pacc[6]*rz + b1.z; r[7] = pacc[7]*rz + b1.w;

  float s1 = 0.f, s2 = 0.f;
  #pragma unroll
  for (int k = 0; k < 8; ++k){ s1 += r[k]; s2 += r[k]*r[k]; }
  #pragma unroll
  for (int off = 1; off < 16; off <<= 1){
    s1 += __shfl_xor(s1, off);
    s2 += __shfl_xor(s2, off);
  }
  float mean = s1 * (1.f/128.f);
  float var  = s2 * (1.f/128.f) - mean*mean;
  float inv  = rsqrtf(var + 1e-5f);

  float4 w0 = *(const float4*)(lnw + c16*8);
  float4 w1 = *(const float4*)(lnw + c16*8 + 4);
  float4 l0 = *(const float4*)(lnb + c16*8);
  float4 l1 = *(const float4*)(lnb + c16*8 + 4);
  float y[8];
  y[0] = fmaxf((r[0]-mean)*inv*w0.x + l0.x, 0.f); y[1] = fmaxf((r[1]-mean)*inv*w0.y + l0.y, 0.f);
  y[2] = fmaxf((r[2]-mean)*inv*w0.z + l0.z, 0.f); y[3] = fmaxf((r[3]-mean)*inv*w0.w + l0.w, 0.f);
  y[4] = fmaxf((r[4]-mean)*inv*w1.x + l1.x, 0.f); y[5] = fmaxf((r[5]-mean)*inv*w1.y + l1.y, 0.f);
  y[6] = fmaxf((r[6]-mean)*inv*w1.z + l1.z, 0.f); y[7] = fmaxf((r[7]-mean)*inv*w1.w + l1.w, 0.f);
  uint4 o;
  unsigned int* op = (unsigned int*)&o;
  #pragma unroll
  for (int q = 0; q < 4; ++q)
    op[q] = (unsigned int)f2b(y[2*q]) | ((unsigned int)f2b(y[2*q+1]) << 16);
  orow[c16] = o;

  // ---- fused next-layer es/ed from f32 y (removes next layer's esed pass) ----
  if (fuse){
    float4 e4 = {0.f,0.f,0.f,0.f}, d4 = {0.f,0.f,0.f,0.f};
    #pragma unroll
    for (int j = 0; j < 8; ++j){
      int c = c16*8 + j;
      float yv = y[j];
      float4 wsv = *(const float4*)(wsN + (size_t)c*4);
      float4 wdv = *(const float4*)(wdN + (size_t)c*4);
      e4.x += yv*wsv.x; e4.y += yv*wsv.y; e4.z += yv*wsv.z; e4.w += yv*wsv.w;
      d4.x += yv*wdv.x; d4.y += yv*wdv.y; d4.z += yv*wdv.z; d4.w += yv*wdv.w;
    }
    #pragma unroll
    for (int off = 1; off < 16; off <<= 1){
      e4.x += __shfl_xor(e4.x, off); e4.y += __shfl_xor(e4.y, off);
      e4.z += __shfl_xor(e4.z, off); e4.w += __shfl_xor(e4.w, off);
      d4.x += __shfl_xor(d4.x, off); d4.y += __shfl_xor(d4.y, off);
      d4.z += __shfl_xor(d4.z, off); d4.w += __shfl_xor(d4.w, off);
    }
    if (c16 == 0)      *(float4*)(esN + (size_t)node*4) = e4;
    else if (c16 == 1) *(float4*)(edN + (size_t)node*4) = d4;
  }
}

// ---------------- final: out[B x OUT] = x[:B] @ lin_w + lin_b (f32 out) ----------------
__global__ __launch_bounds__(256) void hg_final(const unsigned short* __restrict__ x,
                                                const float* __restrict__ w,
                                                const float* __restrict__ b,
                                                float* __restrict__ out, int total, int OUTC){
  int t = blockIdx.x * 256 + threadIdx.x;
  if (t >= total) return;
  int r = t / OUTC, c = t % OUTC;
  const unsigned short* xr = x + (size_t)r * CH;
  float acc = b[c];
  #pragma unroll 8
  for (int k = 0; k < CH; ++k)
    acc += b2f(xr[k]) * w[(size_t)k * OUTC + c];
  out[t] = acc;
}

extern "C" void kernel_launch(void* const* d_in, const int* in_sizes, int n_in,
                              void* d_out, int out_size, void* d_ws, size_t ws_size,
                              hipStream_t stream){
  const float* x_user_f = (const float*)d_in[0];
  const float* x_item_f = (const float*)d_in[1];
  const int* ui_src = (const int*)d_in[2];
  const int* ui_dst = (const int*)d_in[3];
  const int* iu_src = (const int*)d_in[4];
  const int* iu_dst = (const int*)d_in[5];
  const float* Wsrc_ui = (const float*)d_in[6];
  const float* Wdst_ui = (const float*)d_in[7];
  const float* asrc_ui = (const float*)d_in[8];
  const float* adst_ui = (const float*)d_in[9];
  const float* b_ui    = (const float*)d_in[10];
  const float* Wsrc_iu = (const float*)d_in[11];
  const float* Wdst_iu = (const float*)d_in[12];
  const float* asrc_iu = (const float*)d_in[13];
  const float* adst_iu = (const float*)d_in[14];
  const float* b_iu    = (const float*)d_in[15];
  const float* ln_w_user = (const float*)d_in[16];
  const float* ln_b_user = (const float*)d_in[17];
  const float* ln_w_item = (const float*)d_in[18];
  const float* ln_b_item = (const float*)d_in[19];
  const float* lin_w = (const float*)d_in[20];
  const float* lin_b = (const float*)d_in[21];

  const int NU = in_sizes[0] / CH;
  const int NI = in_sizes[1] / CH;
  const int E  = in_sizes[2];
  const int Lnum = in_sizes[6] / (CH*CH);
  const int OUTC = in_sizes[21];
  const int Bn = out_size / OUTC;

  const int NUp = ((NU + 127) / 128) * 128;
  const int NIp = ((NI + 127) / 128) * 128;

  char* ws = (char*)d_ws;
  size_t off = 0;
  auto alloc = [&](size_t bytes)->char*{
    size_t r = (off + 255) & ~(size_t)255;
    off = r + bytes;
    return ws + r;
  };
  unsigned short* xu0 = (unsigned short*)alloc((size_t)NUp * CH * 2);
  unsigned short* xu1 = (unsigned short*)alloc((size_t)NUp * CH * 2);
  unsigned short* xi0 = (unsigned short*)alloc((size_t)NIp * CH * 2);
  unsigned short* xi1 = (unsigned short*)alloc((size_t)NIp * CH * 2);
  unsigned short* hsI = (unsigned short*)alloc((size_t)NIp * CH * 2);
  unsigned short* hsU = (unsigned short*)alloc((size_t)NUp * CH * 2);
  // double-buffered es/ed (layer-parity ping-pong; fused epilogue writes the other set)
  float* esI_[2]; float* esU_[2]; float* edU_[2]; float* edI_[2];
  for (int p = 0; p < 2; ++p){
    esI_[p] = (float*)alloc((size_t)NIp * 4 * 4);
    esU_[p] = (float*)alloc((size_t)NUp * 4 * 4);
    edU_[p] = (float*)alloc((size_t)NUp * 4 * 4);
    edI_[p] = (float*)alloc((size_t)NIp * 4 * 4);
  }
  unsigned short* wtAll = (unsigned short*)alloc((size_t)Lnum * 2 * CH * CH * 2);
  float* wdAll = (float*)alloc((size_t)Lnum * 2 * CH * 4 * 4);
  float* wsAll = (float*)alloc((size_t)Lnum * 2 * CH * 4 * 4);
  int* cntAll = (int*)alloc((size_t)(NU + NI + 2) * 4);
  int* cnt_u = cntAll;
  int* cnt_i = cntAll + NU;
  int* spN_u = cntAll + NU + NI;
  int* spN_i = cntAll + NU + NI + 1;
  int* slots_u = (int*)alloc((size_t)NU * CAP * 4);
  int* slots_i = (int*)alloc((size_t)NI * CAP * 4);
  int* spD_u = (int*)alloc((size_t)E * 4);
  int* spS_u = (int*)alloc((size_t)E * 4);
  int* spD_i = (int*)alloc((size_t)E * 4);
  int* spS_i = (int*)alloc((size_t)E * 4);

  // --- zero counters, then bucket scatter (standalone) ---
  hipMemsetAsync(cntAll, 0, (size_t)(NU + NI + 2) * 4, stream);
  {
    int half = cdiv_i(E, 256);
    hg_bscat<<<dim3(2*half), dim3(256), 0, stream>>>(
        iu_dst, iu_src, cnt_u, slots_u, spN_u, spD_u, spS_u,
        ui_dst, ui_src, cnt_i, slots_i, spN_i, spD_i, spS_i, E, half);
  }
  // --- prep1: cvt || wprep ---
  {
    int bu = cdiv_i(NUp*CH/4, 256), bi = cdiv_i(NIp*CH/4, 256);
    int wp = Lnum*2*68;
    hg_prep1<<<dim3(bu + bi + wp), dim3(256), 0, stream>>>(
        x_user_f, xu0, (long)NU*CH, (long)NUp*CH, bu,
        x_item_f, xi0, (long)NI*CH, (long)NIp*CH, bi,
        Wsrc_iu, Wsrc_ui, Wdst_iu, Wdst_ui,
        asrc_iu, asrc_ui, adst_iu, adst_ui,
        wtAll, wdAll, wsAll);
  }

  unsigned short *xuA = xu0, *xuB = xu1, *xiA = xi0, *xiB = xi1;
  const int nbkI = NIp/128, nbkU = NUp/128;
  const int bU_esed = cdiv_i(NU, 256), bI_esed = cdiv_i(NI, 256);
  const int aggU = NUp/16, aggI = NIp/16;

  for (int l = 0; l < Lnum; ++l){
    size_t ao = (size_t)l * CH;
    int rs = l & 1, wsx = rs ^ 1;
    const unsigned short* wtA = wtAll + (size_t)(l*2 + 0) * CH * CH;
    const unsigned short* wtB = wtAll + (size_t)(l*2 + 1) * CH * CH;
    const float* wdA = wdAll + (size_t)(l*2 + 0) * CH * 4;
    const float* wdB = wdAll + (size_t)(l*2 + 1) * CH * 4;
    const float* wsA = wsAll + (size_t)(l*2 + 0) * CH * 4;
    const float* wsB = wsAll + (size_t)(l*2 + 1) * CH * 4;

    if (l == 0){
      // gemm + esed blocks (layer-0 es/ed from x0)
      hg_gemm2<<<dim3(nbkI + nbkU + bU_esed + bI_esed), dim3(256), 0, stream>>>(
          xiA, wtA, hsI, nbkI,
          xuA, wtB, hsU, nbkI + nbkU,
          wsB, wdA, esU_[rs], edU_[rs], NU, bU_esed,
          wsA, wdB, esI_[rs], edI_[rs], NI);
    } else {
      // gemm only (es/ed produced by previous agg2's fused epilogue)
      hg_gemm2<<<dim3(nbkI + nbkU), dim3(256), 0, stream>>>(
          xiA, wtA, hsI, nbkI,
          xuA, wtB, hsU, nbkI + nbkU,
          wsB, wdA, esU_[rs], edU_[rs], NU, 0,
          wsA, wdB, esI_[rs], edI_[rs], NI);
    }

    // next-layer weight pointers for fused es/ed (valid only when fuse=1)
    int fuse = (l + 1 < Lnum) ? 1 : 0;
    int ln = fuse ? (l + 1) : l;
    const float* wsNA = wsAll + (size_t)(ln*2 + 0) * CH * 4;
    const float* wsNB = wsAll + (size_t)(ln*2 + 1) * CH * 4;
    const float* wdNA = wdAll + (size_t)(ln*2 + 0) * CH * 4;
    const float* wdNB = wdAll + (size_t)(ln*2 + 1) * CH * 4;

    hg_agg2<<<dim3(aggU + aggI), dim3(256), 0, stream>>>(
        cnt_u, slots_u, spN_u, spD_u, spS_u, esI_[rs], edU_[rs], hsI,
        b_iu + ao, ln_w_user + ao, ln_b_user + ao, xuB, NU, aggU,
        wsNB, wdNA, esU_[wsx], edU_[wsx],
        cnt_i, slots_i, spN_i, spD_i, spS_i, esU_[rs], edI_[rs], hsU,
        b_ui + ao, ln_w_item + ao, ln_b_item + ao, xiB, NI,
        wsNA, wdNB, esI_[wsx], edI_[wsx],
        fuse);

    unsigned short* t;
    t = xuA; xuA = xuB; xuB = t;
    t = xiA; xiA = xiB; xiB = t;
  }

  hg_final<<<dim3(cdiv_i(Bn*OUTC,256)), dim3(256), 0, stream>>>(xuA, lin_w, lin_b, (float*)d_out, Bn*OUTC, OUTC);
}

// Round 14
// 351.634 us; speedup vs baseline: 1.2604x; 1.2604x over previous
//
#include <hip/hip_runtime.h>

#define CH 128
#define NHEAD 4
#define CAP 16

typedef float f32x4 __attribute__((ext_vector_type(4)));
typedef short bf16x8 __attribute__((ext_vector_type(8)));

static __device__ __forceinline__ float b2f(unsigned short u){
  union { unsigned int u; float f; } x; x.u = ((unsigned int)u) << 16; return x.f;
}
static __device__ __forceinline__ unsigned short f2b(float f){
  union { float f; unsigned int u; } x; x.f = f;
  unsigned int r = x.u + 0x7FFFu + ((x.u >> 16) & 1u);
  return (unsigned short)(r >> 16);
}

static __host__ __device__ inline int cdiv_i(int a, int b){ return (a + b - 1) / b; }

// ---------------- bucket scatter: one atomic pass builds per-node edge lists ----------------
// pos = atomicAdd(cnt[d]); pos < CAP -> slots[d*CAP+pos] = src; else spill list (correctness fallback)
__global__ __launch_bounds__(256) void hg_bscat(
    const int* __restrict__ dstU, const int* __restrict__ srcU,
    int* __restrict__ cntU, int* __restrict__ slotsU,
    int* __restrict__ spNU, int* __restrict__ spDU, int* __restrict__ spSU,
    const int* __restrict__ dstI, const int* __restrict__ srcI,
    int* __restrict__ cntI, int* __restrict__ slotsI,
    int* __restrict__ spNI, int* __restrict__ spDI, int* __restrict__ spSI,
    int E, int half){
  int b = blockIdx.x;
  const int *dst, *src; int *cnt, *slots, *spN, *spD, *spS; int lb;
  if (b < half){ dst=dstU; src=srcU; cnt=cntU; slots=slotsU; spN=spNU; spD=spDU; spS=spSU; lb=b; }
  else { dst=dstI; src=srcI; cnt=cntI; slots=slotsI; spN=spNI; spD=spDI; spS=spSI; lb=b-half; }
  int t = lb*256 + threadIdx.x;
  if (t >= E) return;
  int d = dst[t], s = src[t];
  int pos = atomicAdd(&cnt[d], 1);
  if (pos < CAP){
    slots[(size_t)d*CAP + pos] = s;
  } else {
    int sp = atomicAdd(spN, 1);
    spD[sp] = d; spS[sp] = s;
  }
}

// ---------------- prep1: cvt (both tensors) || wprep ----------------
__global__ __launch_bounds__(256) void hg_prep1(
    const float* __restrict__ xu, unsigned short* __restrict__ yu, long nuv, long nut, int bu,
    const float* __restrict__ xi, unsigned short* __restrict__ yi, long niv, long nit, int bi,
    const float* __restrict__ Wsrc_iu, const float* __restrict__ Wsrc_ui,
    const float* __restrict__ Wdst_iu, const float* __restrict__ Wdst_ui,
    const float* __restrict__ asrc_iu, const float* __restrict__ asrc_ui,
    const float* __restrict__ adst_iu, const float* __restrict__ adst_ui,
    unsigned short* __restrict__ wtAll, float* __restrict__ wdAll, float* __restrict__ wsAll){
  int b = blockIdx.x, tid = threadIdx.x;
  if (b < bu + bi){
    // ---- cvt ----
    const float* x; unsigned short* y; long nv, nt; int lb;
    if (b < bu){ x = xu; y = yu; nv = nuv; nt = nut; lb = b; }
    else { x = xi; y = yi; nv = niv; nt = nit; lb = b - bu; }
    long t = ((long)lb * 256 + tid) * 4;
    if (t >= nt) return;
    ushort4 o;
    if (t + 3 < nv){
      float4 v = *(const float4*)(x + t);
      o.x = f2b(v.x); o.y = f2b(v.y); o.z = f2b(v.z); o.w = f2b(v.w);
    } else {
      o.x = o.y = o.z = o.w = 0;
    }
    *(ushort4*)(y + t) = o;
  } else {
    // ---- wprep ----
    int wb = b - bu - bi;
    int ld = wb / 68, r = wb % 68;
    int l = ld >> 1, d = ld & 1;
    const float* Ws = (d ? Wsrc_ui : Wsrc_iu) + (size_t)l*CH*CH;
    const float* Wd = (d ? Wdst_ui : Wdst_iu) + (size_t)l*CH*CH;
    const float* as_ = (d ? asrc_ui : asrc_iu) + (size_t)l*CH;
    const float* ad  = (d ? adst_ui : adst_iu) + (size_t)l*CH;
    unsigned short* wt = wtAll + (size_t)ld*CH*CH;
    float* wd_o = wdAll + (size_t)ld*CH*4;
    float* ws_o = wsAll + (size_t)ld*CH*4;
    if (r < 64){
      int t = r*256 + tid;
      int k = t >> 7, n = t & 127;
      wt[n*CH + k] = f2b(Ws[t]);
    } else if (r < 66){
      int t = (r - 64)*256 + tid;
      int k = t >> 2, h = t & 3;
      float acc = 0.f;
      #pragma unroll 8
      for (int c = 0; c < 32; ++c) acc += Wd[k*CH + h*32 + c] * ad[h*32 + c];
      wd_o[k*4 + h] = acc;
    } else {
      int t = (r - 66)*256 + tid;
      int k = t >> 2, h = t & 3;
      float acc = 0.f;
      #pragma unroll 8
      for (int c = 0; c < 32; ++c) acc += Ws[k*CH + h*32 + c] * as_[h*32 + c];
      ws_o[k*4 + h] = acc;
    }
  }
}

// ---------------- GEMM both directions + esed blocks appended to the same grid ----------------
__global__ __launch_bounds__(256) void hg_gemm2(const unsigned short* __restrict__ X0,
                                                const unsigned short* __restrict__ W0,
                                                unsigned short* __restrict__ Y0, int n0,
                                                const unsigned short* __restrict__ X1,
                                                const unsigned short* __restrict__ W1,
                                                unsigned short* __restrict__ Y1, int n01,
                                                const float* __restrict__ wsU, const float* __restrict__ wdU,
                                                float* __restrict__ esU, float* __restrict__ edU, int NU, int bU,
                                                const float* __restrict__ wsI, const float* __restrict__ wdI,
                                                float* __restrict__ esI, float* __restrict__ edI, int NI){
  __shared__ unsigned short Abuf[CH*CH];
  __shared__ unsigned short Bbuf[CH*CH];
  int tid = threadIdx.x;
  int b = blockIdx.x;

  if (b >= n01){
    // ---- esed path ----
    int eb = b - n01;
    const unsigned short* x; const float *wsf, *wdf; float *es, *ed; int N, lb;
    if (eb < bU){ x = X1; wsf = wsU; wdf = wdU; es = esU; ed = edU; N = NU; lb = eb; }
    else { x = X0; wsf = wsI; wdf = wdI; es = esI; ed = edI; N = NI; lb = eb - bU; }
    int n = lb * 256 + tid;
    if (n >= N) return;
    const uint4* row = (const uint4*)(x + (size_t)n * CH);
    float s0=0.f,s1=0.f,s2=0.f,s3=0.f,d0=0.f,d1=0.f,d2=0.f,d3=0.f;
    #pragma unroll
    for (int b8 = 0; b8 < 16; ++b8){
      uint4 v = row[b8];
      unsigned int u[4] = {v.x, v.y, v.z, v.w};
      #pragma unroll
      for (int q = 0; q < 4; ++q){
        int k = b8*8 + 2*q;
        float x0 = b2f((unsigned short)(u[q] & 0xffffu));
        float x1 = b2f((unsigned short)(u[q] >> 16));
        float4 a0 = *(const float4*)(wsf + (size_t)k*4);
        float4 a1 = *(const float4*)(wsf + (size_t)(k+1)*4);
        float4 c0 = *(const float4*)(wdf + (size_t)k*4);
        float4 c1 = *(const float4*)(wdf + (size_t)(k+1)*4);
        s0 += x0*a0.x + x1*a1.x;  s1 += x0*a0.y + x1*a1.y;
        s2 += x0*a0.z + x1*a1.z;  s3 += x0*a0.w + x1*a1.w;
        d0 += x0*c0.x + x1*c1.x;  d1 += x0*c0.y + x1*c1.y;
        d2 += x0*c0.z + x1*c1.z;  d3 += x0*c0.w + x1*c1.w;
      }
    }
    float* eo = es + (size_t)n*4;
    eo[0]=s0; eo[1]=s1; eo[2]=s2; eo[3]=s3;
    float* do_ = ed + (size_t)n*4;
    do_[0]=d0; do_[1]=d1; do_[2]=d2; do_[3]=d3;
    return;
  }

  // ---- GEMM path ----
  size_t bm = b;
  const unsigned short* X; const unsigned short* W; unsigned short* Y;
  if ((int)bm < n0){ X = X0; W = W0; Y = Y0; }
  else { X = X1; W = W1; Y = Y1; bm -= n0; }
  const unsigned short* xsrc = X + bm * (size_t)(CH*CH);
  #pragma unroll
  for (int it = 0; it < 8; ++it){
    int G = it*256 + tid;
    int m = G >> 4, kg = G & 15;
    int sw = kg ^ (m & 7);
    uint4 va = ((const uint4*)xsrc)[G];
    ((uint4*)Abuf)[m*16 + sw] = va;
    uint4 vb = ((const uint4*)W)[G];
    ((uint4*)Bbuf)[m*16 + sw] = vb;
  }
  __syncthreads();

  int lane = tid & 63, wid = tid >> 6;
  int wr = wid >> 1, wc = wid & 1;
  int l15 = lane & 15, l4 = lane >> 4;
  f32x4 acc[4][4] = {};

  #pragma unroll
  for (int kk = 0; kk < 4; ++kk){
    int kgq = kk*4 + l4;
    bf16x8 af[4], bfr[4];
    #pragma unroll
    for (int i = 0; i < 4; ++i){
      int r = wr*64 + i*16 + l15;
      af[i] = *(const bf16x8*)&Abuf[(r*16 + (kgq ^ (r & 7))) * 8];
      int c = wc*64 + i*16 + l15;
      bfr[i] = *(const bf16x8*)&Bbuf[(c*16 + (kgq ^ (c & 7))) * 8];
    }
    #pragma unroll
    for (int i = 0; i < 4; ++i)
      #pragma unroll
      for (int j = 0; j < 4; ++j)
        acc[i][j] = __builtin_amdgcn_mfma_f32_16x16x32_bf16(af[i], bfr[j], acc[i][j], 0, 0, 0);
  }

  #pragma unroll
  for (int i = 0; i < 4; ++i){
    #pragma unroll
    for (int j = 0; j < 4; ++j){
      int r0 = wr*64 + i*16 + l4*4;
      int c  = wc*64 + j*16 + l15;
      size_t base = (bm*CH + r0) * (size_t)CH + c;
      #pragma unroll
      for (int v = 0; v < 4; ++v)
        Y[base + (size_t)v*CH] = f2b(acc[i][j][v]);
    }
  }
}

// ---------------- fused agg: 4 nodes/wave; bucket edge lists; unconditional clamped gathers ----------------
#define AGG_ROUND(DEPTH)                                                          \
  for (int j0 = 0; j0 < nb16; j0 += DEPTH){                                       \
    uint4 hv[DEPTH]; float lg[DEPTH];                                             \
    _Pragma("unroll")                                                             \
    for (int k = 0; k < DEPTH; ++k){                                              \
      int jk = j0 + k; jk = (jk < nb16) ? jk : (nb16 - 1);                        \
      int s = __shfl(sj, g*16 + jk);                                              \
      hv[k] = *(const uint4*)(hs + (size_t)s*CH + c16*8);                         \
      lg[k] = eslog[(size_t)s*4 + h];                                             \
    }                                                                             \
    _Pragma("unroll")                                                             \
    for (int k = 0; k < DEPTH; ++k){                                              \
      float ev = lg[k] + edv;                                                     \
      ev = (ev > 0.f) ? ev : 0.2f * ev;                                           \
      float w = ((j0 + k) < nb16) ? __expf(ev) : 0.f;                             \
      zp += w;                                                                    \
      unsigned int u0 = hv[k].x, u1 = hv[k].y, u2 = hv[k].z, u3 = hv[k].w;        \
      pacc[0] += w * b2f((unsigned short)(u0 & 0xffffu));                         \
      pacc[1] += w * b2f((unsigned short)(u0 >> 16));                             \
      pacc[2] += w * b2f((unsigned short)(u1 & 0xffffu));                         \
      pacc[3] += w * b2f((unsigned short)(u1 >> 16));                             \
      pacc[4] += w * b2f((unsigned short)(u2 & 0xffffu));                         \
      pacc[5] += w * b2f((unsigned short)(u2 >> 16));                             \
      pacc[6] += w * b2f((unsigned short)(u3 & 0xffffu));                         \
      pacc[7] += w * b2f((unsigned short)(u3 >> 16));                             \
    }                                                                             \
  }

__global__ __launch_bounds__(256) void hg_agg2(
    const int* __restrict__ cntU, const int* __restrict__ slotsU,
    const int* __restrict__ spNU, const int* __restrict__ spDU, const int* __restrict__ spSU,
    const float* __restrict__ eslogU, const float* __restrict__ edU,
    const unsigned short* __restrict__ hsI,
    const float* __restrict__ biasU, const float* __restrict__ lnwU, const float* __restrict__ lnbU,
    unsigned short* __restrict__ xoutU, int NU, int nbU,
    const int* __restrict__ cntI, const int* __restrict__ slotsI,
    const int* __restrict__ spNI, const int* __restrict__ spDI, const int* __restrict__ spSI,
    const float* __restrict__ eslogI, const float* __restrict__ edI,
    const unsigned short* __restrict__ hsU,
    const float* __restrict__ biasI, const float* __restrict__ lnwI, const float* __restrict__ lnbI,
    unsigned short* __restrict__ xoutI, int NI){
  int b = blockIdx.x;
  bool isU = (b < nbU);
  const int *cnt, *slots, *spN, *spD, *spS; const float *eslog, *ed;
  const unsigned short* hs; const float *bias, *lnw, *lnb;
  unsigned short* xout; int Ndst, lb;
  if (isU){
    cnt = cntU; slots = slotsU; spN = spNU; spD = spDU; spS = spSU;
    eslog = eslogU; ed = edU; hs = hsI;
    bias = biasU; lnw = lnwU; lnb = lnbU; xout = xoutU; Ndst = NU; lb = b;
  } else {
    cnt = cntI; slots = slotsI; spN = spNI; spD = spDI; spS = spSI;
    eslog = eslogI; ed = edI; hs = hsU;
    bias = biasI; lnw = lnwI; lnb = lnbI; xout = xoutI; Ndst = NI; lb = b - nbU;
  }
  int tid = threadIdx.x;
  int lane = tid & 63, wid = tid >> 6;
  int g = lane >> 4, c16 = lane & 15, h = c16 >> 2;
  int node = lb * 16 + wid * 4 + g;
  uint4* orow = (uint4*)(xout + (size_t)node * CH);
  if (node >= Ndst){
    uint4 z4 = {0,0,0,0};
    orow[c16] = z4;
    return;
  }

  int deg = cnt[node];
  float edv = ed[(size_t)node*4 + h];
  float pacc[8] = {0.f,0.f,0.f,0.f,0.f,0.f,0.f,0.f};
  float zp = 0.f;

  int nb16 = deg < CAP ? deg : CAP;
  const int* sl = slots + (size_t)node * CAP;
  int jj = (c16 < nb16) ? c16 : (nb16 > 0 ? nb16 - 1 : 0);
  int sj = sl[jj];

  if (isU){
    AGG_ROUND(8)
  } else {
    AGG_ROUND(4)
  }
  // rare spill tail (deg > CAP): scan the (tiny) spill list for this node's edges
  if (deg > CAP){
    int sn = *spN;
    for (int j = 0; j < sn; ++j){
      if (spD[j] == node){
        int s = spS[j];
        float ev = eslog[(size_t)s*4 + h] + edv;
        ev = (ev > 0.f) ? ev : 0.2f * ev;
        float w = __expf(ev);
        zp += w;
        uint4 hv1 = *(const uint4*)(hs + (size_t)s*CH + c16*8);
        unsigned int u[4] = {hv1.x, hv1.y, hv1.z, hv1.w};
        #pragma unroll
        for (int q = 0; q < 4; ++q){
          pacc[2*q]   += w * b2f((unsigned short)(u[q] & 0xffffu));
          pacc[2*q+1] += w * b2f((unsigned short)(u[q] >> 16));
        }
      }
    }
  }

  float rz = (zp > 0.f) ? (1.f / zp) : 0.f;
  float4 b0 = *(const float4*)(bias + c16*8);
  float4 b1 = *(const float4*)(bias + c16*8 + 4);
  float r[8];
  r[0] = pacc[0]*rz + b0.x; r[1] = pacc[1]*rz + b0.y;
  r[2] = pacc[2]*rz + b0.z; r[3] = pacc[3]*rz + b0.w;
  r[4] = pacc[4]*rz + b1.x; r[5] = pacc[5]*rz + b1.y;
  r[6] = pacc[6]*rz + b1.z; r[7] = pacc[7]*rz + b1.w;

  float s1 = 0.f, s2 = 0.f;
  #pragma unroll
  for (int k = 0; k < 8; ++k){ s1 += r[k]; s2 += r[k]*r[k]; }
  #pragma unroll
  for (int off = 1; off < 16; off <<= 1){
    s1 += __shfl_xor(s1, off);
    s2 += __shfl_xor(s2, off);
  }
  float mean = s1 * (1.f/128.f);
  float var  = s2 * (1.f/128.f) - mean*mean;
  float inv  = rsqrtf(var + 1e-5f);

  float4 w0 = *(const float4*)(lnw + c16*8);
  float4 w1 = *(const float4*)(lnw + c16*8 + 4);
  float4 l0 = *(const float4*)(lnb + c16*8);
  float4 l1 = *(const float4*)(lnb + c16*8 + 4);
  float y[8];
  y[0] = (r[0]-mean)*inv*w0.x + l0.x; y[1] = (r[1]-mean)*inv*w0.y + l0.y;
  y[2] = (r[2]-mean)*inv*w0.z + l0.z; y[3] = (r[3]-mean)*inv*w0.w + l0.w;
  y[4] = (r[4]-mean)*inv*w1.x + l1.x; y[5] = (r[5]-mean)*inv*w1.y + l1.y;
  y[6] = (r[6]-mean)*inv*w1.z + l1.z; y[7] = (r[7]-mean)*inv*w1.w + l1.w;
  uint4 o;
  unsigned int* op = (unsigned int*)&o;
  #pragma unroll
  for (int q = 0; q < 4; ++q){
    float a = fmaxf(y[2*q], 0.f), bb = fmaxf(y[2*q+1], 0.f);
    op[q] = (unsigned int)f2b(a) | ((unsigned int)f2b(bb) << 16);
  }
  orow[c16] = o;
}

// ---------------- final: out[B x OUT] = x[:B] @ lin_w + lin_b (f32 out) ----------------
__global__ __launch_bounds__(256) void hg_final(const unsigned short* __restrict__ x,
                                                const float* __restrict__ w,
                                                const float* __restrict__ b,
                                                float* __restrict__ out, int total, int OUTC){
  int t = blockIdx.x * 256 + threadIdx.x;
  if (t >= total) return;
  int r = t / OUTC, c = t % OUTC;
  const unsigned short* xr = x + (size_t)r * CH;
  float acc = b[c];
  #pragma unroll 8
  for (int k = 0; k < CH; ++k)
    acc += b2f(xr[k]) * w[(size_t)k * OUTC + c];
  out[t] = acc;
}

extern "C" void kernel_launch(void* const* d_in, const int* in_sizes, int n_in,
                              void* d_out, int out_size, void* d_ws, size_t ws_size,
                              hipStream_t stream){
  const float* x_user_f = (const float*)d_in[0];
  const float* x_item_f = (const float*)d_in[1];
  const int* ui_src = (const int*)d_in[2];
  const int* ui_dst = (const int*)d_in[3];
  const int* iu_src = (const int*)d_in[4];
  const int* iu_dst = (const int*)d_in[5];
  const float* Wsrc_ui = (const float*)d_in[6];
  const float* Wdst_ui = (const float*)d_in[7];
  const float* asrc_ui = (const float*)d_in[8];
  const float* adst_ui = (const float*)d_in[9];
  const float* b_ui    = (const float*)d_in[10];
  const float* Wsrc_iu = (const float*)d_in[11];
  const float* Wdst_iu = (const float*)d_in[12];
  const float* asrc_iu = (const float*)d_in[13];
  const float* adst_iu = (const float*)d_in[14];
  const float* b_iu    = (const float*)d_in[15];
  const float* ln_w_user = (const float*)d_in[16];
  const float* ln_b_user = (const float*)d_in[17];
  const float* ln_w_item = (const float*)d_in[18];
  const float* ln_b_item = (const float*)d_in[19];
  const float* lin_w = (const float*)d_in[20];
  const float* lin_b = (const float*)d_in[21];

  const int NU = in_sizes[0] / CH;
  const int NI = in_sizes[1] / CH;
  const int E  = in_sizes[2];
  const int Lnum = in_sizes[6] / (CH*CH);
  const int OUTC = in_sizes[21];
  const int Bn = out_size / OUTC;

  const int NUp = ((NU + 127) / 128) * 128;
  const int NIp = ((NI + 127) / 128) * 128;

  char* ws = (char*)d_ws;
  size_t off = 0;
  auto alloc = [&](size_t bytes)->char*{
    size_t r = (off + 255) & ~(size_t)255;
    off = r + bytes;
    return ws + r;
  };
  unsigned short* xu0 = (unsigned short*)alloc((size_t)NUp * CH * 2);
  unsigned short* xu1 = (unsigned short*)alloc((size_t)NUp * CH * 2);
  unsigned short* xi0 = (unsigned short*)alloc((size_t)NIp * CH * 2);
  unsigned short* xi1 = (unsigned short*)alloc((size_t)NIp * CH * 2);
  unsigned short* hsI = (unsigned short*)alloc((size_t)NIp * CH * 2);
  unsigned short* hsU = (unsigned short*)alloc((size_t)NUp * CH * 2);
  float* esIb = (float*)alloc((size_t)NIp * 4 * 4);
  float* esUb = (float*)alloc((size_t)NUp * 4 * 4);
  float* edU  = (float*)alloc((size_t)NUp * 4 * 4);
  float* edI  = (float*)alloc((size_t)NIp * 4 * 4);
  unsigned short* wtAll = (unsigned short*)alloc((size_t)Lnum * 2 * CH * CH * 2);
  float* wdAll = (float*)alloc((size_t)Lnum * 2 * CH * 4 * 4);
  float* wsAll = (float*)alloc((size_t)Lnum * 2 * CH * 4 * 4);
  // bucket structures (replaces CSR): cnt_u | cnt_i | spillN_u | spillN_i contiguous for one memset
  int* cntAll = (int*)alloc((size_t)(NU + NI + 2) * 4);
  int* cnt_u = cntAll;
  int* cnt_i = cntAll + NU;
  int* spN_u = cntAll + NU + NI;
  int* spN_i = cntAll + NU + NI + 1;
  int* slots_u = (int*)alloc((size_t)NU * CAP * 4);
  int* slots_i = (int*)alloc((size_t)NI * CAP * 4);
  int* spD_u = (int*)alloc((size_t)E * 4);
  int* spS_u = (int*)alloc((size_t)E * 4);
  int* spD_i = (int*)alloc((size_t)E * 4);
  int* spS_i = (int*)alloc((size_t)E * 4);

  // --- zero counters, then bucket scatter (standalone: atomics + random stores) ---
  hipMemsetAsync(cntAll, 0, (size_t)(NU + NI + 2) * 4, stream);
  {
    int half = cdiv_i(E, 256);
    hg_bscat<<<dim3(2*half), dim3(256), 0, stream>>>(
        iu_dst, iu_src, cnt_u, slots_u, spN_u, spD_u, spS_u,
        ui_dst, ui_src, cnt_i, slots_i, spN_i, spD_i, spS_i, E, half);
  }
  // --- prep1: cvt || wprep ---
  {
    int bu = cdiv_i(NUp*CH/4, 256), bi = cdiv_i(NIp*CH/4, 256);
    int wp = Lnum*2*68;
    hg_prep1<<<dim3(bu + bi + wp), dim3(256), 0, stream>>>(
        x_user_f, xu0, (long)NU*CH, (long)NUp*CH, bu,
        x_item_f, xi0, (long)NI*CH, (long)NIp*CH, bi,
        Wsrc_iu, Wsrc_ui, Wdst_iu, Wdst_ui,
        asrc_iu, asrc_ui, adst_iu, adst_ui,
        wtAll, wdAll, wsAll);
  }

  unsigned short *xuA = xu0, *xuB = xu1, *xiA = xi0, *xiB = xi1;
  const int nbkI = NIp/128, nbkU = NUp/128;
  const int bU_esed = cdiv_i(NU, 256), bI_esed = cdiv_i(NI, 256);
  const int aggU = NUp/16, aggI = NIp/16;

  for (int l = 0; l < Lnum; ++l){
    size_t ao = (size_t)l * CH;
    const unsigned short* wtA = wtAll + (size_t)(l*2 + 0) * CH * CH;
    const unsigned short* wtB = wtAll + (size_t)(l*2 + 1) * CH * CH;
    const float* wdA = wdAll + (size_t)(l*2 + 0) * CH * 4;
    const float* wdB = wdAll + (size_t)(l*2 + 1) * CH * 4;
    const float* wsA = wsAll + (size_t)(l*2 + 0) * CH * 4;
    const float* wsB = wsAll + (size_t)(l*2 + 1) * CH * 4;

    hg_gemm2<<<dim3(nbkI + nbkU + bU_esed + bI_esed), dim3(256), 0, stream>>>(
        xiA, wtA, hsI, nbkI,
        xuA, wtB, hsU, nbkI + nbkU,
        wsB, wdA, esUb, edU, NU, bU_esed,
        wsA, wdB, esIb, edI, NI);
    hg_agg2<<<dim3(aggU + aggI), dim3(256), 0, stream>>>(
        cnt_u, slots_u, spN_u, spD_u, spS_u, esIb, edU, hsI,
        b_iu + ao, ln_w_user + ao, ln_b_user + ao, xuB, NU, aggU,
        cnt_i, slots_i, spN_i, spD_i, spS_i, esUb, edI, hsU,
        b_ui + ao, ln_w_item + ao, ln_b_item + ao, xiB, NI);

    unsigned short* t;
    t = xuA; xuA = xuB; xuB = t;
    t = xiA; xiA = xiB; xiB = t;
  }

  hg_final<<<dim3(cdiv_i(Bn*OUTC,256)), dim3(256), 0, stream>>>(xuA, lin_w, lin_b, (float*)d_out, Bn*OUTC, OUTC);
}